// Round 7
// baseline (298.882 us; speedup 1.0000x reference)
//
#include <hip/hip_runtime.h>
#include <hip/hip_cooperative_groups.h>

namespace cg = cooperative_groups;

// VQ-EMA forward for z:(32,64,32,32) fp32, 1024 codes of dim 64.
// Outputs (flat, fp32): z_q (2097152) | loss (1) | counts (1024)
// ONE cooperative kernel: zero+enorm | dist+argmin+counts/sums | ema | gather | loss.

#define N_ROWS   32768
#define N_CODES  1024
#define ZQ_ELEMS 2097152
#define NSPLIT   4
#define ZERO_FLOATS (NSPLIT * (N_CODES + 65536))   // counts + sums copies

// ---- fragment helpers (verbatim from measured R6 vq_dist) -----------------
__device__ __forceinline__ void ldfrag(float4 (&dst)[8], const float4* __restrict__ s4,
                                       int lane, int g) {
    #pragma unroll
    for (int r = 0; r < 8; ++r) dst[r] = s4[(lane + 16 * r) * 17 + g];
}
__device__ __forceinline__ void fma_tile(const float4 (&zf)[8], const float4 (&ef)[8],
                                         float (&acc)[8][8]) {
    #pragma unroll
    for (int rr = 0; rr < 8; ++rr)
        #pragma unroll
        for (int j = 0; j < 8; ++j) {
            float a = acc[rr][j];
            a = fmaf(zf[rr].x, ef[j].x, a);
            a = fmaf(zf[rr].y, ef[j].y, a);
            a = fmaf(zf[rr].z, ef[j].z, a);
            a = fmaf(zf[rr].w, ef[j].w, a);
            acc[rr][j] = a;
        }
}

__global__ __launch_bounds__(256, 2) void vq_fused(
        const float* __restrict__ z, const float* __restrict__ emb,
        const float* __restrict__ cs, const float* __restrict__ csum,
        float* __restrict__ out, float* __restrict__ counts,
        float* __restrict__ sums, float* __restrict__ enorm_ws,
        float* __restrict__ new_embed, float* __restrict__ partial) {
    __shared__ float zs[128 * 68];     // [row][k] pad 68 (17 float4); lives A->D
    __shared__ float es[128 * 68];
    __shared__ float zn_s[128];
    __shared__ int   idx_sh[128];
    __shared__ float red[4];

    cg::grid_group grid = cg::this_grid();
    const int t   = threadIdx.x;
    const int bid = blockIdx.x;        // 0..255
    const int gid = bid * 256 + t;     // 0..65535

    // ================= phase A: zero accumulators + code norms ============
    for (int i = gid; i < ZERO_FLOATS; i += 65536) counts[i] = 0.f;  // counts|sums contiguous
    if (gid < N_CODES) {
        const float4* __restrict__ e4 = (const float4*)(emb + (gid << 6));
        float s = 0.f;
        #pragma unroll
        for (int i = 0; i < 16; ++i) {            // sequential k chain (as R6)
            const float4 v = e4[i];
            s = fmaf(v.x, v.x, s); s = fmaf(v.y, v.y, s);
            s = fmaf(v.z, v.z, s); s = fmaf(v.w, v.w, s);
        }
        enorm_ws[gid] = s;
    }
    grid.sync();

    // ================= phase B: distance + argmin + counts/sums ===========
    const int tx  = t & 15, ty = t >> 4;
    const int r0  = bid * 128;
    const int b   = r0 >> 10;
    const int hw0 = r0 & 1023;
    const int sp  = bid & (NSPLIT - 1);

    // stage z (coalesced over hw; LDS [row][k])
    #pragma unroll
    for (int i = 0; i < 32; ++i) {
        const int cell = i * 256 + t;
        const int row = cell & 127, c = cell >> 7;
        zs[row * 68 + c] = z[((b * 64 + c) << 10) + hw0 + row];
    }
    __syncthreads();

    // per-row ||z||^2, sequential k
    if (t < 128) {
        const float4* z4 = (const float4*)zs + t * 17;
        float s = 0.f;
        #pragma unroll
        for (int g = 0; g < 16; ++g) {
            const float4 v = z4[g];
            s = fmaf(v.x, v.x, s); s = fmaf(v.y, v.y, s);
            s = fmaf(v.z, v.z, s); s = fmaf(v.w, v.w, s);
        }
        zn_s[t] = s;
    }
    __syncthreads();

    float znr[8];
    #pragma unroll
    for (int rr = 0; rr < 8; ++rr) znr[rr] = zn_s[ty + 16 * rr];

    float best[8]; int bidx[8];
    #pragma unroll
    for (int rr = 0; rr < 8; ++rr) { best[rr] = INFINITY; bidx[rr] = 0; }

    const float4* __restrict__ eg  = (const float4*)emb;
    const float4* __restrict__ zs4 = (const float4*)zs;
    const float4* __restrict__ es4 = (const float4*)es;

    for (int ch = 0; ch < 8; ++ch) {              // all 1024 codes, ascending
        const int cbase = ch << 7;
        float4 pf[8];
        #pragma unroll
        for (int p = 0; p < 8; ++p) pf[p] = eg[ch * 2048 + p * 256 + t];
        float enj[8];
        #pragma unroll
        for (int j = 0; j < 8; ++j) enj[j] = enorm_ws[cbase + tx + 16 * j];

        __syncthreads();                           // previous chunk consumed
        #pragma unroll
        for (int p = 0; p < 8; ++p) {
            const int fid = p * 256 + t;
            ((float4*)es)[(fid >> 4) * 17 + (fid & 15)] = pf[p];
        }
        __syncthreads();

        float acc[8][8];
        #pragma unroll
        for (int rr = 0; rr < 8; ++rr)
            #pragma unroll
            for (int j = 0; j < 8; ++j) acc[rr][j] = 0.f;

        float4 zf[8], efA[8], efB[8];
        ldfrag(efA, es4, tx, 0);
        #pragma unroll
        for (int gp = 0; gp < 8; ++gp) {
            ldfrag(zf, zs4, ty, 2 * gp);
            ldfrag(efB, es4, tx, 2 * gp + 1);
            fma_tile(zf, efA, acc);
            ldfrag(zf, zs4, ty, 2 * gp + 1);
            if (gp < 7) ldfrag(efA, es4, tx, 2 * gp + 2);
            fma_tile(zf, efB, acc);
        }

        #pragma unroll
        for (int rr = 0; rr < 8; ++rr)
            #pragma unroll
            for (int j = 0; j < 8; ++j) {
                const float s = (znr[rr] + enj[j]) - 2.0f * acc[rr][j];
                if (s < best[rr]) { best[rr] = s; bidx[rr] = cbase + tx + 16 * j; }
            }
    }

    // argmin reduce across the 16 tx lanes (tie -> lower code index)
    #pragma unroll
    for (int off = 1; off < 16; off <<= 1) {
        #pragma unroll
        for (int rr = 0; rr < 8; ++rr) {
            const float os = __shfl_xor(best[rr], off);
            const int   oi = __shfl_xor(bidx[rr], off);
            if (os < best[rr] || (os == best[rr] && oi < bidx[rr])) {
                best[rr] = os; bidx[rr] = oi;
            }
        }
    }
    if (tx == 0) {
        #pragma unroll
        for (int rr = 0; rr < 8; ++rr) {
            idx_sh[ty + 16 * rr] = bidx[rr];
            atomicAdd(&counts[sp * N_CODES + bidx[rr]], 1.0f);
        }
    }
    __syncthreads();

    // fused segment-sum scatter (z already in LDS)
    {
        const int k = t & 63, sub = t >> 6;
        #pragma unroll
        for (int i = 0; i < 32; ++i) {
            const int row = i * 4 + sub;
            atomicAdd(&sums[sp * 65536 + idx_sh[row] * 64 + k], zs[row * 68 + k]);
        }
    }
    grid.sync();

    // ================= phase C: EMA -> new_embed; counts out ==============
    {
        const int c = gid >> 6, d = gid & 63;
        const float cnt = (counts[c] + counts[N_CODES + c])
                        + (counts[2 * N_CODES + c] + counts[3 * N_CODES + c]);
        const float ssum = (sums[gid] + sums[65536 + gid])
                         + (sums[131072 + gid] + sums[196608 + gid]);
        const float nsize = 0.99f * cs[c] + 0.01f * cnt;
        const float nsum  = 0.99f * csum[gid] + 0.01f * ssum;
        new_embed[gid] = nsum / (nsize + 1e-5f);
        if (d == 0) out[ZQ_ELEMS + 1 + c] = cnt;       // counts output
    }
    grid.sync();

    // ================= phase D: gather z_q from resident zs + loss ========
    {
        const int row = t >> 1, d0 = (t & 1) << 5;     // 2 threads per row
        const int code = idx_sh[row];
        const float4* __restrict__ er = (const float4*)(new_embed + (code << 6) + d0);
        float4 e4[8];
        #pragma unroll
        for (int i = 0; i < 8; ++i) e4[i] = er[i];

        float lsum = 0.f;
        #pragma unroll
        for (int i = 0; i < 32; ++i) {
            const int c = d0 + i;
            const float e  = ((const float*)e4)[i];
            const float zv = zs[row * 68 + c];
            const float diff = e - zv;                 // z_q - zp (fp32)
            out[((b * 64 + c) << 10) + hw0 + row] = zv + diff;   // straight-through
            lsum = fmaf(diff, diff, lsum);
        }
        #pragma unroll
        for (int off = 32; off >= 1; off >>= 1) lsum += __shfl_down(lsum, off);
        if ((t & 63) == 0) red[t >> 6] = lsum;
        __syncthreads();
        if (t == 0) partial[bid] = (red[0] + red[1]) + (red[2] + red[3]);
    }
    grid.sync();

    // ================= phase E: loss reduction (block 0) ==================
    if (bid == 0) {
        float v = partial[t];                          // t covers 0..255
        #pragma unroll
        for (int off = 32; off >= 1; off >>= 1) v += __shfl_down(v, off);
        if ((t & 63) == 0) red[t >> 6] = v;
        __syncthreads();
        if (t == 0) {
            const float s = (red[0] + red[1]) + (red[2] + red[3]);
            out[ZQ_ELEMS] = s * (0.25f / 2097152.0f);  // BETA / 2^21, exact scale
        }
    }
}

// ---------------------------------------------------------------------------
extern "C" void kernel_launch(void* const* d_in, const int* in_sizes, int n_in,
                              void* d_out, int out_size, void* d_ws, size_t ws_size,
                              hipStream_t stream) {
    const float* z    = (const float*)d_in[0];   // (32,64,32,32)
    const float* emb  = (const float*)d_in[1];   // (1024,64)
    const float* cs   = (const float*)d_in[2];   // (1024,)
    const float* csum = (const float*)d_in[3];   // (1024,64)
    float* out = (float*)d_out;

    // ws layout (all float)
    float* counts     = (float*)d_ws;                  // NSPLIT*1024   } zeroed
    float* sums       = counts + NSPLIT * N_CODES;     // NSPLIT*65536  } in phase A
    float* enorm_ws   = sums + NSPLIT * 65536;         // 1024
    float* new_embed  = enorm_ws + N_CODES;            // 65536
    float* partial    = new_embed + 65536;             // 256

    void* args[] = {(void*)&z, (void*)&emb, (void*)&cs, (void*)&csum,
                    (void*)&out, (void*)&counts, (void*)&sums, (void*)&enorm_ws,
                    (void*)&new_embed, (void*)&partial};
    hipLaunchCooperativeKernel((void*)vq_fused, dim3(256), dim3(256), args, 0, stream);
}

// Round 8
// 182.977 us; speedup vs baseline: 1.6334x; 1.6334x over previous
//
#include <hip/hip_runtime.h>
#include <hip/hip_bf16.h>

// VQ-EMA forward for z:(32,64,32,32) fp32, 1024 codes of dim 64.
// Outputs (flat, fp32): z_q (2097152) | loss (1) | counts (1024)
// Distance GEMM runs on MFMA via EXACT 3-way bf16 split of both operands.

#define N_ROWS   32768
#define N_CODES  1024
#define ZQ_ELEMS 2097152
#define NSPLIT   4
#define ZERO_N   (NSPLIT * (N_CODES + 65536))     // counts + sums

typedef __attribute__((ext_vector_type(8))) short short8;   // 8 bf16 (4 VGPR)
typedef __attribute__((ext_vector_type(4))) float f32x4;

// round-to-nearest-even fp32 -> bf16 bits (no NaN in this data)
__device__ __forceinline__ unsigned short f2bf(float x) {
    unsigned u = __float_as_uint(x);
    return (unsigned short)((u + 0x7fffu + ((u >> 16) & 1u)) >> 16);
}
__device__ __forceinline__ float bf2f(unsigned short h) {
    return __uint_as_float(((unsigned)h) << 16);
}

// ---------------- kernel 1: zero accs | split emb -> 3 bf16 planes | enorm --
__global__ void vq_prep(const float* __restrict__ emb, float* __restrict__ zero_base,
                        unsigned short* __restrict__ eH, unsigned short* __restrict__ eM,
                        unsigned short* __restrict__ eL, float* __restrict__ enorm) {
    const int g = blockIdx.x * 256 + threadIdx.x;
    if (g < ZERO_N) {
        zero_base[g] = 0.f;
    } else if (g < ZERO_N + 65536) {
        const int i = g - ZERO_N;                  // element of emb
        const float f = emb[i];
        const unsigned short h = f2bf(f);
        const float r1 = f - bf2f(h);
        const unsigned short m = f2bf(r1);
        const float r2 = r1 - bf2f(m);
        const unsigned short l = f2bf(r2);         // exact: f == hf+mf+lf
        eH[i] = h; eM[i] = m; eL[i] = l;
    } else if (g < ZERO_N + 65536 + N_CODES) {
        const int c = g - ZERO_N - 65536;
        const float4* __restrict__ e4 = (const float4*)(emb + (c << 6));
        float s = 0.f;
        #pragma unroll
        for (int i = 0; i < 16; ++i) {             // sequential k (ref chain)
            const float4 v = e4[i];
            s = fmaf(v.x, v.x, s); s = fmaf(v.y, v.y, s);
            s = fmaf(v.z, v.z, s); s = fmaf(v.w, v.w, s);
        }
        enorm[c] = s;
    }
}

// ---------------- kernel 2: MFMA distance + argmin + fused counts/sums -----
// 256 blocks x 1024 thr (16 waves, 1 block/CU, 4 waves/SIMD).
// Block: 128 rows x 1024 codes. Wave w: rows (w&7)*16, code-half (w>>3).
#define MFMA_BF16 __builtin_amdgcn_mfma_f32_16x16x32_bf16

__global__ __launch_bounds__(1024) void vq_dist(
        const float* __restrict__ z,
        const unsigned short* __restrict__ eH, const unsigned short* __restrict__ eM,
        const unsigned short* __restrict__ eL, const float* __restrict__ enorm,
        int* __restrict__ idx_out, float* __restrict__ counts,
        float* __restrict__ sums) {
    __shared__ unsigned short zH[128 * 72];   // [row][k] pad 72 (16B-aligned rows)
    __shared__ unsigned short zM[128 * 72];
    __shared__ unsigned short zL[128 * 72];
    __shared__ float en_lds[N_CODES];
    __shared__ float bestS[2][128];
    __shared__ int   idxS[2][128];
    __shared__ int   idx_sh[128];

    const int t    = threadIdx.x;
    const int bid  = blockIdx.x;
    const int r0   = bid * 128;
    const int b    = r0 >> 10;
    const int hw0  = r0 & 1023;
    const int sp   = bid & (NSPLIT - 1);

    // ---- stage z: read BCHW coalesced, split to 3 bf16 planes in LDS ----
    #pragma unroll
    for (int i = 0; i < 8; ++i) {
        const int cell = i * 1024 + t;
        const int row = cell & 127, c = cell >> 7;
        const float f = z[((b * 64 + c) << 10) + hw0 + row];
        const unsigned short h = f2bf(f);
        const float r1 = f - bf2f(h);
        const unsigned short m = f2bf(r1);
        const float r2 = r1 - bf2f(m);
        zH[row * 72 + c] = h;
        zM[row * 72 + c] = m;
        zL[row * 72 + c] = f2bf(r2);              // exact 3-way split
    }
    if (t < N_CODES) en_lds[t] = enorm[t];
    __syncthreads();

    const int lane = t & 63, wid = t >> 6;
    const int wrow = (wid & 7) * 16;              // wave's 16-row strip
    const int half = wid >> 3;                    // 0: codes 0-511, 1: 512-1023
    const int lr   = lane & 15, lk = lane >> 4;   // frag row/col, k-group

    // ---- hoist A-fragments (z) for the whole code scan: 6 x bf16x8 ----
    const int abase = (wrow + lr) * 72 + lk * 8;
    const short8 aH0 = *(const short8*)&zH[abase];
    const short8 aH1 = *(const short8*)&zH[abase + 32];
    const short8 aM0 = *(const short8*)&zM[abase];
    const short8 aM1 = *(const short8*)&zM[abase + 32];
    const short8 aL0 = *(const short8*)&zL[abase];
    const short8 aL1 = *(const short8*)&zL[abase + 32];

    float best[4] = {INFINITY, INFINITY, INFINITY, INFINITY};
    int   bidx[4] = {0, 0, 0, 0};

    const int co = lr * 64 + lk * 8;              // per-lane offset into e planes

    // ---- 32 code-tiles (16 codes), 2 per iteration for MFMA ILP ----
    for (int pair = 0; pair < 16; ++pair) {
        const int c0 = half * 512 + pair * 32;    // tile0: c0, tile1: c0+16
        const int e0 = c0 * 64 + co, e1 = e0 + 1024;

        const short8 b0H0 = *(const short8*)&eH[e0];
        const short8 b0H1 = *(const short8*)&eH[e0 + 32];
        const short8 b0M0 = *(const short8*)&eM[e0];
        const short8 b0M1 = *(const short8*)&eM[e0 + 32];
        const short8 b0L0 = *(const short8*)&eL[e0];
        const short8 b0L1 = *(const short8*)&eL[e0 + 32];
        const short8 b1H0 = *(const short8*)&eH[e1];
        const short8 b1H1 = *(const short8*)&eH[e1 + 32];
        const short8 b1M0 = *(const short8*)&eM[e1];
        const short8 b1M1 = *(const short8*)&eM[e1 + 32];
        const short8 b1L0 = *(const short8*)&eL[e1];
        const short8 b1L1 = *(const short8*)&eL[e1 + 32];

        f32x4 acc0 = {0.f, 0.f, 0.f, 0.f};
        f32x4 acc1 = {0.f, 0.f, 0.f, 0.f};
        // 6 plane products x 2 k-steps, two independent chains interleaved
        acc0 = MFMA_BF16(aH0, b0H0, acc0, 0, 0, 0);
        acc1 = MFMA_BF16(aH0, b1H0, acc1, 0, 0, 0);
        acc0 = MFMA_BF16(aH1, b0H1, acc0, 0, 0, 0);
        acc1 = MFMA_BF16(aH1, b1H1, acc1, 0, 0, 0);
        acc0 = MFMA_BF16(aH0, b0M0, acc0, 0, 0, 0);
        acc1 = MFMA_BF16(aH0, b1M0, acc1, 0, 0, 0);
        acc0 = MFMA_BF16(aH1, b0M1, acc0, 0, 0, 0);
        acc1 = MFMA_BF16(aH1, b1M1, acc1, 0, 0, 0);
        acc0 = MFMA_BF16(aM0, b0H0, acc0, 0, 0, 0);
        acc1 = MFMA_BF16(aM0, b1H0, acc1, 0, 0, 0);
        acc0 = MFMA_BF16(aM1, b0H1, acc0, 0, 0, 0);
        acc1 = MFMA_BF16(aM1, b1H1, acc1, 0, 0, 0);
        acc0 = MFMA_BF16(aM0, b0M0, acc0, 0, 0, 0);
        acc1 = MFMA_BF16(aM0, b1M0, acc1, 0, 0, 0);
        acc0 = MFMA_BF16(aM1, b0M1, acc0, 0, 0, 0);
        acc1 = MFMA_BF16(aM1, b1M1, acc1, 0, 0, 0);
        acc0 = MFMA_BF16(aH0, b0L0, acc0, 0, 0, 0);
        acc1 = MFMA_BF16(aH0, b1L0, acc1, 0, 0, 0);
        acc0 = MFMA_BF16(aH1, b0L1, acc0, 0, 0, 0);
        acc1 = MFMA_BF16(aH1, b1L1, acc1, 0, 0, 0);
        acc0 = MFMA_BF16(aL0, b0H0, acc0, 0, 0, 0);
        acc1 = MFMA_BF16(aL0, b1H0, acc1, 0, 0, 0);
        acc0 = MFMA_BF16(aL1, b0H1, acc0, 0, 0, 0);
        acc1 = MFMA_BF16(aL1, b1H1, acc1, 0, 0, 0);

        // ---- scores (en - 2*dot; row-constant ||z||^2 dropped) ----
        const float en0 = en_lds[c0 + lr];
        const float en1 = en_lds[c0 + 16 + lr];
        #pragma unroll
        for (int i = 0; i < 4; ++i) {
            const float s0 = en0 - 2.0f * acc0[i];
            if (s0 < best[i]) { best[i] = s0; bidx[i] = c0 + lr; }
            const float s1 = en1 - 2.0f * acc1[i];
            if (s1 < best[i]) { best[i] = s1; bidx[i] = c0 + 16 + lr; }
        }
    }

    // ---- argmin across the 16 cols sharing rows (tie -> lower index) ----
    #pragma unroll
    for (int off = 1; off < 16; off <<= 1) {
        #pragma unroll
        for (int i = 0; i < 4; ++i) {
            const float os = __shfl_xor(best[i], off);
            const int   oi = __shfl_xor(bidx[i], off);
            if (os < best[i] || (os == best[i] && oi < bidx[i])) {
                best[i] = os; bidx[i] = oi;
            }
        }
    }
    if (lr == 0) {
        #pragma unroll
        for (int i = 0; i < 4; ++i) {
            const int row = wrow + lk * 4 + i;    // C/D row = (lane>>4)*4+reg
            bestS[half][row] = best[i];
            idxS[half][row]  = bidx[i];
        }
    }
    __syncthreads();

    // ---- resolve halves + counts ----
    if (t < 128) {
        const float s0 = bestS[0][t], s1 = bestS[1][t];
        const int   bi = (s1 < s0) ? idxS[1][t] : idxS[0][t];  // tie -> half 0
        idx_sh[t] = bi;
        idx_out[r0 + t] = bi;
        atomicAdd(&counts[sp * N_CODES + bi], 1.0f);
    }
    __syncthreads();

    // ---- fused segment-sum scatter (z == (zH+zM)+zL exactly) ----
    {
        const int k = t & 63, sub = t >> 6;
        #pragma unroll
        for (int i = 0; i < 8; ++i) {
            const int row = i * 16 + sub;
            const int o = row * 72 + k;
            const float v = (bf2f(zH[o]) + bf2f(zM[o])) + bf2f(zL[o]);
            atomicAdd(&sums[sp * 65536 + idx_sh[row] * 64 + k], v);
        }
    }
}

// ---------------- kernel 3: EMA update -> new_embed; counts out; loss=0 ----
__global__ void vq_ema(const float* __restrict__ counts, const float* __restrict__ sums,
                       const float* __restrict__ cs, const float* __restrict__ csum,
                       float* __restrict__ new_embed, float* __restrict__ out_counts,
                       float* __restrict__ out_loss) {
    const int g = blockIdx.x * 256 + threadIdx.x;   // 0 .. 65535
    const int c = g >> 6, d = g & 63;
    const float cnt = (counts[c] + counts[N_CODES + c])
                    + (counts[2 * N_CODES + c] + counts[3 * N_CODES + c]);
    const float ssum = (sums[g] + sums[65536 + g]) + (sums[131072 + g] + sums[196608 + g]);
    const float nsize = 0.99f * cs[c] + 0.01f * cnt;
    const float nsum  = 0.99f * csum[g] + 0.01f * ssum;
    new_embed[g] = nsum / (nsize + 1e-5f);
    if (d == 0) out_counts[c] = cnt;
    if (g == 0) out_loss[0] = 0.f;
}

// ---------------- kernel 4: gather z_q, straight-through, loss -------------
__global__ __launch_bounds__(256) void vq_gather(
        const float* __restrict__ z, const int* __restrict__ idx,
        const float* __restrict__ new_embed,
        float* __restrict__ out_zq, float* __restrict__ out_loss) {
    __shared__ float red[4];
    const int t  = threadIdx.x;
    const int r0 = blockIdx.x * 256;
    const int b  = r0 >> 10;
    const int hw = (r0 & 1023) + t;
    const int myidx = idx[r0 + t];

    const float4* __restrict__ er = (const float4*)(new_embed + (myidx << 6));
    float4 e4[16];
    #pragma unroll
    for (int i = 0; i < 16; ++i) e4[i] = er[i];

    float lsum = 0.f;
    #pragma unroll
    for (int c = 0; c < 64; ++c) {
        const float e  = ((const float*)e4)[c];
        const int  off = ((b * 64 + c) << 10) + hw;
        const float zv = z[off];
        const float diff = e - zv;                    // z_q - zp (fp32)
        out_zq[off] = zv + diff;                      // straight-through
        lsum = fmaf(diff, diff, lsum);
    }
    #pragma unroll
    for (int off = 32; off >= 1; off >>= 1) lsum += __shfl_down(lsum, off);
    if ((t & 63) == 0) red[t >> 6] = lsum;
    __syncthreads();
    if (t == 0) {
        const float s = red[0] + red[1] + red[2] + red[3];
        atomicAdd(out_loss, s * (0.25f / 2097152.0f));   // BETA/2^21 exact
    }
}

// ---------------------------------------------------------------------------
extern "C" void kernel_launch(void* const* d_in, const int* in_sizes, int n_in,
                              void* d_out, int out_size, void* d_ws, size_t ws_size,
                              hipStream_t stream) {
    const float* z    = (const float*)d_in[0];   // (32,64,32,32)
    const float* emb  = (const float*)d_in[1];   // (1024,64)
    const float* cs   = (const float*)d_in[2];   // (1024,)
    const float* csum = (const float*)d_in[3];   // (1024,64)
    float* out = (float*)d_out;

    // ws layout (floats)
    float* counts     = (float*)d_ws;                    // NSPLIT*1024   } zeroed
    float* sums       = counts + NSPLIT * N_CODES;       // NSPLIT*65536  } in prep
    float* enorm_ws   = sums + NSPLIT * 65536;           // 1024
    float* new_embed  = enorm_ws + N_CODES;              // 65536
    int*   idx        = (int*)(new_embed + 65536);       // 32768 ints
    unsigned short* eH = (unsigned short*)(idx + 32768); // 65536 bf16 each
    unsigned short* eM = eH + 65536;
    unsigned short* eL = eM + 65536;

    // prep: zero (266240) | split emb (65536) | enorm (1024) => 332800 items
    vq_prep<<<1300, 256, 0, stream>>>(emb, counts, eH, eM, eL, enorm_ws);
    vq_dist<<<256, 1024, 0, stream>>>(z, eH, eM, eL, enorm_ws, idx, counts, sums);
    vq_ema<<<256, 256, 0, stream>>>(counts, sums, cs, csum, new_embed,
                                    out + ZQ_ELEMS + 1,   // counts out
                                    out + ZQ_ELEMS);      // loss out
    vq_gather<<<128, 256, 0, stream>>>(z, idx, new_embed, out, out + ZQ_ELEMS);
}

// Round 10
// 140.409 us; speedup vs baseline: 2.1287x; 1.3032x over previous
//
#include <hip/hip_runtime.h>
#include <hip/hip_bf16.h>

// VQ-EMA forward for z:(32,64,32,32) fp32, 1024 codes of dim 64.
// Outputs (flat, fp32): z_q (2097152) | loss (1) | counts (1024)
// Distance GEMM on MFMA via EXACT 3-way bf16 split; e-planes staged via LDS.

#define N_ROWS   32768
#define N_CODES  1024
#define ZQ_ELEMS 2097152
#define NSPLIT   4
#define ZERO_N   (NSPLIT * (N_CODES + 65536))     // counts + sums

typedef __attribute__((ext_vector_type(8))) short short8;   // 8 bf16 (4 VGPR)
typedef __attribute__((ext_vector_type(4))) float f32x4;

__device__ __forceinline__ unsigned short f2bf(float x) {
    unsigned u = __float_as_uint(x);
    return (unsigned short)((u + 0x7fffu + ((u >> 16) & 1u)) >> 16);
}
__device__ __forceinline__ float bf2f(unsigned short h) {
    return __uint_as_float(((unsigned)h) << 16);
}

// ---------------- kernel 1: zero accs | split emb -> 3 bf16 planes | enorm --
__global__ void vq_prep(const float* __restrict__ emb, float* __restrict__ zero_base,
                        unsigned short* __restrict__ eH, unsigned short* __restrict__ eM,
                        unsigned short* __restrict__ eL, float* __restrict__ enorm) {
    const int g = blockIdx.x * 256 + threadIdx.x;
    if (g < ZERO_N) {
        zero_base[g] = 0.f;
    } else if (g < ZERO_N + 65536) {
        const int i = g - ZERO_N;
        const float f = emb[i];
        const unsigned short h = f2bf(f);
        const float r1 = f - bf2f(h);
        const unsigned short m = f2bf(r1);
        const float r2 = r1 - bf2f(m);
        eH[i] = h; eM[i] = m; eL[i] = f2bf(r2);    // exact: f == H+M+L
    } else if (g < ZERO_N + 65536 + N_CODES) {
        const int c = g - ZERO_N - 65536;
        const float4* __restrict__ e4 = (const float4*)(emb + (c << 6));
        float s = 0.f;
        #pragma unroll
        for (int i = 0; i < 16; ++i) {             // sequential k (ref chain)
            const float4 v = e4[i];
            s = fmaf(v.x, v.x, s); s = fmaf(v.y, v.y, s);
            s = fmaf(v.z, v.z, s); s = fmaf(v.w, v.w, s);
        }
        enorm[c] = s;
    }
}

// ---------------- kernel 2: MFMA distance + argmin + fused counts/sums -----
// 256 blocks x 1024 thr (16 waves = 4 row-strips x 4 code-groups).
// Block: 128 rows x 1024 codes; 16 chunks of 64 codes staged via LDS.
#define MFMA_BF16 __builtin_amdgcn_mfma_f32_16x16x32_bf16

__global__ __launch_bounds__(1024) void vq_dist(
        const float* __restrict__ z,
        const unsigned short* __restrict__ eH, const unsigned short* __restrict__ eM,
        const unsigned short* __restrict__ eL, const float* __restrict__ enorm,
        int* __restrict__ idx_out, float* __restrict__ counts,
        float* __restrict__ sums) {
    __shared__ unsigned short zH[128 * 72];   // [row][k] pad 72 (16B-aligned rows)
    __shared__ unsigned short zM[128 * 72];
    __shared__ unsigned short zL[128 * 72];
    __shared__ unsigned short esH[64 * 72];   // staged e chunk (64 codes)
    __shared__ unsigned short esM[64 * 72];
    __shared__ unsigned short esL[64 * 72];
    __shared__ float en_lds[N_CODES];
    __shared__ float bestS[4][128];
    __shared__ int   idxS[4][128];
    __shared__ int   idx_sh[128];

    const int t    = threadIdx.x;
    const int bid  = blockIdx.x;
    const int r0   = bid * 128;
    const int b    = r0 >> 10;
    const int hw0  = r0 & 1023;
    const int sp   = bid & (NSPLIT - 1);

    // ---- stage z: read BCHW coalesced, split to 3 bf16 planes in LDS ----
    #pragma unroll
    for (int i = 0; i < 8; ++i) {
        const int cell = i * 1024 + t;
        const int row = cell & 127, c = cell >> 7;
        const float f = z[((b * 64 + c) << 10) + hw0 + row];
        const unsigned short h = f2bf(f);
        const float r1 = f - bf2f(h);
        const unsigned short m = f2bf(r1);
        const float r2 = r1 - bf2f(m);
        zH[row * 72 + c] = h;
        zM[row * 72 + c] = m;
        zL[row * 72 + c] = f2bf(r2);
    }
    en_lds[t] = enorm[t];
    __syncthreads();

    const int lane = t & 63, wid = t >> 6;
    const int wstrip = wid >> 2;              // 0..3 -> rows wstrip*32
    const int cg     = wid & 3;               // 0..3 -> codes cg*16 per chunk
    const int lr = lane & 15, lk = lane >> 4;

    // ---- hoist A-fragments: 2 row-tiles x {H,M,L} x {k0,k1} = 12 short8 ----
    short8 aH[2][2], aM[2][2], aL[2][2];
    #pragma unroll
    for (int tl = 0; tl < 2; ++tl) {
        const int ab = (wstrip * 32 + tl * 16 + lr) * 72 + lk * 8;
        aH[tl][0] = *(const short8*)&zH[ab]; aH[tl][1] = *(const short8*)&zH[ab + 32];
        aM[tl][0] = *(const short8*)&zM[ab]; aM[tl][1] = *(const short8*)&zM[ab + 32];
        aL[tl][0] = *(const short8*)&zL[ab]; aL[tl][1] = *(const short8*)&zL[ab + 32];
    }

    float best[2][4]; int bidx[2][4];
    #pragma unroll
    for (int tl = 0; tl < 2; ++tl)
        #pragma unroll
        for (int i = 0; i < 4; ++i) { best[tl][i] = INFINITY; bidx[tl][i] = 0; }

    // staging map: thread -> (cl, k4): cl = t>>4 (0..63), k4 = t&15
    const int cl = t >> 4, k4 = t & 15;
    const int ebyte = (cl << 6) + k4 * 4;     // element offset into 64-code chunk
    const int dsto  = cl * 72 + k4 * 4;       // LDS dest (short index), 8B aligned
    short4 st0, st1, st2;
    st0 = *(const short4*)&eH[ebyte];
    st1 = *(const short4*)&eM[ebyte];
    st2 = *(const short4*)&eL[ebyte];

    for (int ch = 0; ch < 16; ++ch) {
        __syncthreads();                       // prior chunk fully consumed
        *(short4*)&esH[dsto] = st0;
        *(short4*)&esM[dsto] = st1;
        *(short4*)&esL[dsto] = st2;
        __syncthreads();
        if (ch < 15) {                         // prefetch next chunk (drains under MFMA)
            const int off = (ch + 1) * 4096 + ebyte;
            st0 = *(const short4*)&eH[off];
            st1 = *(const short4*)&eM[off];
            st2 = *(const short4*)&eL[off];
        }

        // ---- B-fragments for this wave's 16 codes ----
        const int bb = (cg * 16 + lr) * 72 + lk * 8;
        const short8 bH0 = *(const short8*)&esH[bb];
        const short8 bH1 = *(const short8*)&esH[bb + 32];
        const short8 bM0 = *(const short8*)&esM[bb];
        const short8 bM1 = *(const short8*)&esM[bb + 32];
        const short8 bL0 = *(const short8*)&esL[bb];
        const short8 bL1 = *(const short8*)&esL[bb + 32];

        f32x4 a0 = {0.f, 0.f, 0.f, 0.f};
        f32x4 a1 = {0.f, 0.f, 0.f, 0.f};
        // product order per acc identical to R8 (bit-identical scores)
        a0 = MFMA_BF16(aH[0][0], bH0, a0, 0, 0, 0);
        a1 = MFMA_BF16(aH[1][0], bH0, a1, 0, 0, 0);
        a0 = MFMA_BF16(aH[0][1], bH1, a0, 0, 0, 0);
        a1 = MFMA_BF16(aH[1][1], bH1, a1, 0, 0, 0);
        a0 = MFMA_BF16(aH[0][0], bM0, a0, 0, 0, 0);
        a1 = MFMA_BF16(aH[1][0], bM0, a1, 0, 0, 0);
        a0 = MFMA_BF16(aH[0][1], bM1, a0, 0, 0, 0);
        a1 = MFMA_BF16(aH[1][1], bM1, a1, 0, 0, 0);
        a0 = MFMA_BF16(aM[0][0], bH0, a0, 0, 0, 0);
        a1 = MFMA_BF16(aM[1][0], bH0, a1, 0, 0, 0);
        a0 = MFMA_BF16(aM[0][1], bH1, a0, 0, 0, 0);
        a1 = MFMA_BF16(aM[1][1], bH1, a1, 0, 0, 0);
        a0 = MFMA_BF16(aM[0][0], bM0, a0, 0, 0, 0);
        a1 = MFMA_BF16(aM[1][0], bM0, a1, 0, 0, 0);
        a0 = MFMA_BF16(aM[0][1], bM1, a0, 0, 0, 0);
        a1 = MFMA_BF16(aM[1][1], bM1, a1, 0, 0, 0);
        a0 = MFMA_BF16(aH[0][0], bL0, a0, 0, 0, 0);
        a1 = MFMA_BF16(aH[1][0], bL0, a1, 0, 0, 0);
        a0 = MFMA_BF16(aH[0][1], bL1, a0, 0, 0, 0);
        a1 = MFMA_BF16(aH[1][1], bL1, a1, 0, 0, 0);
        a0 = MFMA_BF16(aL[0][0], bH0, a0, 0, 0, 0);
        a1 = MFMA_BF16(aL[1][0], bH0, a1, 0, 0, 0);
        a0 = MFMA_BF16(aL[0][1], bH1, a0, 0, 0, 0);
        a1 = MFMA_BF16(aL[1][1], bH1, a1, 0, 0, 0);

        // ---- scores (en - 2*dot; row-constant ||z||^2 dropped) ----
        const int code = ch * 64 + cg * 16 + lr;     // strictly ascending in ch
        const float en_c = en_lds[code];
        #pragma unroll
        for (int i = 0; i < 4; ++i) {
            const float s0 = en_c - 2.0f * a0[i];
            if (s0 < best[0][i]) { best[0][i] = s0; bidx[0][i] = code; }
            const float s1 = en_c - 2.0f * a1[i];
            if (s1 < best[1][i]) { best[1][i] = s1; bidx[1][i] = code; }
        }
    }

    // ---- argmin across the 16 lr lanes (tie -> lower code index) ----
    #pragma unroll
    for (int off = 1; off < 16; off <<= 1) {
        #pragma unroll
        for (int tl = 0; tl < 2; ++tl)
            #pragma unroll
            for (int i = 0; i < 4; ++i) {
                const float os = __shfl_xor(best[tl][i], off);
                const int   oi = __shfl_xor(bidx[tl][i], off);
                if (os < best[tl][i] || (os == best[tl][i] && oi < bidx[tl][i])) {
                    best[tl][i] = os; bidx[tl][i] = oi;
                }
            }
    }
    if (lr == 0) {
        #pragma unroll
        for (int tl = 0; tl < 2; ++tl)
            #pragma unroll
            for (int i = 0; i < 4; ++i) {
                const int row = wstrip * 32 + tl * 16 + lk * 4 + i;  // C/D row map
                bestS[cg][row] = best[tl][i];
                idxS[cg][row]  = bidx[tl][i];
            }
    }
    __syncthreads();

    // ---- resolve code-groups (score, then lower-index tie-break) ----
    if (t < 128) {
        float bs = bestS[0][t]; int bi = idxS[0][t];
        #pragma unroll
        for (int g = 1; g < 4; ++g) {
            const float s = bestS[g][t]; const int ix = idxS[g][t];
            if (s < bs || (s == bs && ix < bi)) { bs = s; bi = ix; }
        }
        idx_sh[t] = bi;
        idx_out[r0 + t] = bi;
        atomicAdd(&counts[sp * N_CODES + bi], 1.0f);
    }
    __syncthreads();

    // ---- fused segment-sum scatter (z == (H+M)+L exactly) ----
    {
        const int k = t & 63, sub = t >> 6;
        #pragma unroll
        for (int i = 0; i < 8; ++i) {
            const int row = i * 16 + sub;
            const int o = row * 72 + k;
            const float v = (bf2f(zH[o]) + bf2f(zM[o])) + bf2f(zL[o]);
            atomicAdd(&sums[sp * 65536 + idx_sh[row] * 64 + k], v);
        }
    }
}

// ---------------- kernel 3: EMA update -> new_embed; counts out; loss=0 ----
__global__ void vq_ema(const float* __restrict__ counts, const float* __restrict__ sums,
                       const float* __restrict__ cs, const float* __restrict__ csum,
                       float* __restrict__ new_embed, float* __restrict__ out_counts,
                       float* __restrict__ out_loss) {
    const int g = blockIdx.x * 256 + threadIdx.x;   // 0 .. 65535
    const int c = g >> 6, d = g & 63;
    const float cnt = (counts[c] + counts[N_CODES + c])
                    + (counts[2 * N_CODES + c] + counts[3 * N_CODES + c]);
    const float ssum = (sums[g] + sums[65536 + g]) + (sums[131072 + g] + sums[196608 + g]);
    const float nsize = 0.99f * cs[c] + 0.01f * cnt;
    const float nsum  = 0.99f * csum[g] + 0.01f * ssum;
    new_embed[g] = nsum / (nsize + 1e-5f);
    if (d == 0) out_counts[c] = cnt;
    if (g == 0) out_loss[0] = 0.f;
}

// ---------------- kernel 4: gather z_q, straight-through, loss -------------
__global__ __launch_bounds__(256) void vq_gather(
        const float* __restrict__ z, const int* __restrict__ idx,
        const float* __restrict__ new_embed,
        float* __restrict__ out_zq, float* __restrict__ out_loss) {
    __shared__ float red[4];
    const int t  = threadIdx.x;
    const int r0 = blockIdx.x * 256;
    const int b  = r0 >> 10;
    const int hw = (r0 & 1023) + t;
    const int myidx = idx[r0 + t];

    const float4* __restrict__ er = (const float4*)(new_embed + (myidx << 6));
    float4 e4[16];
    #pragma unroll
    for (int i = 0; i < 16; ++i) e4[i] = er[i];

    float lsum = 0.f;
    #pragma unroll
    for (int c = 0; c < 64; ++c) {
        const float e  = ((const float*)e4)[c];
        const int  off = ((b * 64 + c) << 10) + hw;
        const float zv = z[off];
        const float diff = e - zv;                    // z_q - zp (fp32)
        out_zq[off] = zv + diff;                      // straight-through
        lsum = fmaf(diff, diff, lsum);
    }
    #pragma unroll
    for (int off = 32; off >= 1; off >>= 1) lsum += __shfl_down(lsum, off);
    if ((t & 63) == 0) red[t >> 6] = lsum;
    __syncthreads();
    if (t == 0) {
        const float s = red[0] + red[1] + red[2] + red[3];
        atomicAdd(out_loss, s * (0.25f / 2097152.0f));   // BETA/2^21 exact
    }
}

// ---------------------------------------------------------------------------
extern "C" void kernel_launch(void* const* d_in, const int* in_sizes, int n_in,
                              void* d_out, int out_size, void* d_ws, size_t ws_size,
                              hipStream_t stream) {
    const float* z    = (const float*)d_in[0];   // (32,64,32,32)
    const float* emb  = (const float*)d_in[1];   // (1024,64)
    const float* cs   = (const float*)d_in[2];   // (1024,)
    const float* csum = (const float*)d_in[3];   // (1024,64)
    float* out = (float*)d_out;

    // ws layout (floats)
    float* counts     = (float*)d_ws;                    // NSPLIT*1024   } zeroed
    float* sums       = counts + NSPLIT * N_CODES;       // NSPLIT*65536  } in prep
    float* enorm_ws   = sums + NSPLIT * 65536;           // 1024
    float* new_embed  = enorm_ws + N_CODES;              // 65536
    int*   idx        = (int*)(new_embed + 65536);       // 32768 ints
    unsigned short* eH = (unsigned short*)(idx + 32768); // 65536 bf16 each
    unsigned short* eM = eH + 65536;
    unsigned short* eL = eM + 65536;

    vq_prep<<<1300, 256, 0, stream>>>(emb, counts, eH, eM, eL, enorm_ws);
    vq_dist<<<256, 1024, 0, stream>>>(z, eH, eM, eL, enorm_ws, idx, counts, sums);
    vq_ema<<<256, 256, 0, stream>>>(counts, sums, cs, csum, new_embed,
                                    out + ZQ_ELEMS + 1,   // counts out
                                    out + ZQ_ELEMS);      // loss out
    vq_gather<<<128, 256, 0, stream>>>(z, idx, new_embed, out, out + ZQ_ELEMS);
}